// Round 10
// baseline (76.234 us; speedup 1.0000x reference)
//
#include <hip/hip_runtime.h>

#define EPS 1e-7f
#define LOG2E 1.44269504088896340736f

typedef float f32x2 __attribute__((ext_vector_type(2)));
typedef float f32x4 __attribute__((ext_vector_type(4)));

constexpr int BLOCK = 1024;        // 16 waves/block; grid 512 -> 2 blocks/CU = 32 waves/CU (8/SIMD)
constexpr int JJ    = 4;           // lane-fast j slots
constexpr int JR    = 4;           // j's per thread
constexpr int JB    = JJ * JR;     // 16 outputs per block
constexpr int SS    = BLOCK / JJ;  // 256 i-segments
constexpr int CHUNK = 1024;        // points per LDS chunk
constexpr int PTS   = CHUNK / SS;  // 4 points per segment (one b128 group)
constexpr int ROW   = 12;          // 48B rows: 16B-aligned, uniform 2-way banks (free, m136)
constexpr int ASZ   = SS * ROW;    // floats per SoA array

// R9 established: total = ~58.2us fixed + kernel; kernel 14.7us, stall-bound
// (VALUBusy 60%, 4 waves/SIMD). This round: (a) 8 waves/SIMD via BLOCK=1024
// at same JB=16 (grid 512 -> 2 blocks/CU, 32 waves/CU; __launch_bounds__
// (1024,2) caps VGPR at 64 -- R4 demand was 56, fits); (b) LDS -25%: drop
// the s=x^2+y^2 array, recompute in-loop (4 pk_fma vs 3). 3 SoA arrays
// (x,y,o), ROW=12; red[256][16] (32KB) aliases the arrays (36.9KB) after
// the sweep. Barriers proven irrelevant (R8==R9), so 2/chunk stays.
__global__ __launch_bounds__(BLOCK, 2) void nw_block(
    const float2* __restrict__ x,        // M x 2 query points
    const float2* __restrict__ inputs,   // N x 2 data points
    const float*  __restrict__ outputs,  // N
    const float*  __restrict__ bw,       // M
    float*        __restrict__ out,      // M
    int N, int M)
{
    __shared__ __align__(16) float smem[3 * ASZ];   // 36.9 KB/block
    float* sX = smem;
    float* sY = smem + ASZ;
    float* sO = smem + 2 * ASZ;

    const int tid = threadIdx.x;
    const int jj  = tid & (JJ - 1);
    const int ss  = tid >> 2;            // segment = row
    const int j0  = blockIdx.x * JB;

    // per-thread coefficient pairs (splat): t = c0*(px^2+py^2) + c1*px + c2*py + c3
    f32x2 c0p[JR], c1p[JR], c2p[JR], c3p[JR];
    #pragma unroll
    for (int r = 0; r < JR; ++r) {
        const int j = j0 + jj + r * JJ;
        float k = 0.f, v1 = 0.f, v2 = 0.f, v3 = 0.f;
        if (j < M) {
            float2 xj = x[j];
            float  b  = bw[j];
            k  = -LOG2E / (2.0f * b * b);              // < 0 (b >= 0.5)
            v1 = -2.0f * k * xj.x;
            v2 = -2.0f * k * xj.y;
            v3 = k * fmaf(xj.x, xj.x, xj.y * xj.y);
        }
        c0p[r] = {k, k}; c1p[r] = {v1, v1}; c2p[r] = {v2, v2}; c3p[r] = {v3, v3};
    }

    f32x2 nump[JR], denp[JR];
    #pragma unroll
    for (int r = 0; r < JR; ++r) { nump[r] = {0.f, 0.f}; denp[r] = {0.f, 0.f}; }

    // register prefetch of chunk 0: thread t owns point t
    float2 pin = make_float2(0.f, 0.f);
    float  po  = 0.f;
    if (tid < N) { pin = inputs[tid]; po = outputs[tid]; }

    for (int base = 0; base < N; base += CHUNK) {
        // stage point (base+tid) -> row tid>>2, col tid&3 (3 b32 writes, 2-way banks)
        {
            const bool v = (base + tid) < N;
            // pad: x=1e19 -> c0*x^2 ~ -1e38 -> t << -150 -> w = 0 (c0<0 for real j)
            sX[ss * ROW + jj] = v ? pin.x : 1.0e19f;
            sY[ss * ROW + jj] = v ? pin.y : 0.f;
            sO[ss * ROW + jj] = v ? po    : 0.f;
        }
        __syncthreads();

        // prefetch next chunk; flies under the compute below
        {
            const int nb = base + CHUNK;
            const int gi = nb + tid;
            if (nb < N && gi < N) { pin = inputs[gi]; po = outputs[gi]; }
        }

        // compute: this segment's 4 points (one b128 per array) x JR j's
        {
            const f32x4 xq = *(const f32x4*)&sX[ss * ROW];   // ds_read_b128, 2-way = free
            const f32x4 yq = *(const f32x4*)&sY[ss * ROW];
            const f32x4 oq = *(const f32x4*)&sO[ss * ROW];
            const f32x2 x0 = {xq.x, xq.y}, x1 = {xq.z, xq.w};
            const f32x2 y0 = {yq.x, yq.y}, y1 = {yq.z, yq.w};
            const f32x2 o0 = {oq.x, oq.y}, o1 = {oq.z, oq.w};
            #pragma unroll
            for (int r = 0; r < JR; ++r) {
                f32x2 Aa = __builtin_elementwise_fma(c0p[r], x0, c1p[r]);
                f32x2 Ba = __builtin_elementwise_fma(c0p[r], y0, c2p[r]);
                f32x2 ta = __builtin_elementwise_fma(Ba, y0, c3p[r]);
                ta = __builtin_elementwise_fma(Aa, x0, ta);
                f32x2 Ab = __builtin_elementwise_fma(c0p[r], x1, c1p[r]);
                f32x2 Bb = __builtin_elementwise_fma(c0p[r], y1, c2p[r]);
                f32x2 tb = __builtin_elementwise_fma(Bb, y1, c3p[r]);
                tb = __builtin_elementwise_fma(Ab, x1, tb);
                f32x2 wa, wb;
                wa.x = __builtin_amdgcn_exp2f(ta.x);
                wa.y = __builtin_amdgcn_exp2f(ta.y);
                wb.x = __builtin_amdgcn_exp2f(tb.x);
                wb.y = __builtin_amdgcn_exp2f(tb.y);
                nump[r] = __builtin_elementwise_fma(wa, o0, nump[r]);
                nump[r] = __builtin_elementwise_fma(wb, o1, nump[r]);
                denp[r] += wa + wb;
            }
        }
        __syncthreads();
    }

    // reduction: red[256][16] float2 (32 KB) aliases smem (safe after trailing barrier)
    float2 (*red)[JB] = (float2 (*)[JB])smem;
    #pragma unroll
    for (int r = 0; r < JR; ++r)
        red[ss][jj + r * JJ] = make_float2(nump[r].x + nump[r].y,
                                           denp[r].x + denp[r].y);
    __syncthreads();
    if (tid < 16 * JB) {                 // 256 threads: (s2 in 0..15, slot in 0..15)
        const int s2   = tid >> 4;
        const int slot = tid & (JB - 1);
        float n = 0.f, d = 0.f;
        #pragma unroll
        for (int k = 0; k < SS / 16; ++k) {
            n += red[s2 + 16 * k][slot].x;
            d += red[s2 + 16 * k][slot].y;
        }
        red[s2][slot] = make_float2(n, d);
    }
    __syncthreads();
    if (tid < JB) {
        float n = 0.f, d = 0.f;
        #pragma unroll
        for (int s = 0; s < 16; ++s) {
            n += red[s][tid].x;
            d += red[s][tid].y;
        }
        const int j = j0 + tid;
        if (j < M) out[j] = n / (d + EPS);
    }
}

extern "C" void kernel_launch(void* const* d_in, const int* in_sizes, int n_in,
                              void* d_out, int out_size, void* d_ws, size_t ws_size,
                              hipStream_t stream) {
    // setup_inputs() dict order: x (M*2), inputs (N*2), outputs (N), bandwidth (M)
    const float2* x       = (const float2*)d_in[0];
    const float2* inputs  = (const float2*)d_in[1];
    const float*  outputs = (const float*) d_in[2];
    const float*  bwv     = (const float*) d_in[3];
    const int N = in_sizes[2];   // outputs element count
    const int M = in_sizes[3];   // bandwidth element count
    float*        out     = (float*)d_out;

    dim3 grid((M + JB - 1) / JB);    // 512 blocks @ M=8192 -> 2 blocks/CU, 32 waves/CU
    nw_block<<<grid, BLOCK, 0, stream>>>(x, inputs, outputs, bwv, out, N, M);
}